// Round 18
// baseline (765.148 us; speedup 1.0000x reference)
//
#include <hip/hip_runtime.h>
#include <hip/hip_bf16.h>
#include <stdint.h>

typedef unsigned short u16;
typedef short v8s __attribute__((ext_vector_type(8)));
typedef float v4f __attribute__((ext_vector_type(4)));
typedef uint32_t v2u __attribute__((ext_vector_type(2)));

#define DIM 192
#define NH 6
#define IMG 224
#define NWIN 28
#define NB 8
#define SCALE 0.17677669529663687f
#define AO_STR 200   // bf16 stride for attn_out tile
#define PPB 2        // window-pairs per block (sequential)

// X-tile swizzle (r9-proven): bijective per token, halves gather-store conflicts
#define SWZ(tok) ((((tok) & 7) ^ ((tok) >> 3)) << 3)

__device__ __forceinline__ u16 f2bf(float f) {
    union { __hip_bfloat16 b; u16 u; } c; c.b = __float2bfloat16(f); return c.u;
}
__device__ __forceinline__ uint32_t pk2(float lo, float hi) {
    union { __hip_bfloat162 b; uint32_t u; } c;
    c.b = __float22bfloat162_rn(make_float2(lo, hi));
    return c.u;
}

// ---- prep: bf16 weights (SCALE folded into q rows), scaled bias, expanded bias table ----
__global__ void prep_kernel(const float* __restrict__ qkv_w,
                            const float* __restrict__ qkv_b,
                            const float* __restrict__ proj_w,
                            const float* __restrict__ rel_bias,
                            const int* __restrict__ rel_idx,
                            u16* __restrict__ qw, u16* __restrict__ pw,
                            float* __restrict__ qb2, float* __restrict__ biasT) {
    int i = blockIdx.x * 256 + threadIdx.x;
    if (i < 3*DIM*DIM) {
        float s = (i < DIM*DIM) ? SCALE : 1.f;
        qw[i] = f2bf(qkv_w[i] * s);
    }
    if (i < DIM*DIM) pw[i] = f2bf(proj_w[i]);
    if (i < 3*DIM)   qb2[i] = qkv_b[i] * (i < DIM ? SCALE : 1.f);
    if (i < NH*64*64) {
        int h   = i >> 12;          // biasT[h][query][key], key minor
        int qk2 = i & 4095;
        biasT[i] = rel_bias[rel_idx[qk2]*NH + h];
    }
}

// ---- fused window attention: one block = 2 pairs x (2 windows x 6 heads = 12 waves) ----
__global__ __launch_bounds__(768, 3) void winattn_kernel(
    const float* __restrict__ x,
    const float* __restrict__ proj_b,
    const u16* __restrict__ qw,
    const u16* __restrict__ pw,
    const float* __restrict__ qb2,
    const float* __restrict__ biasT,
    float* __restrict__ out)
{
    __shared__ __align__(16) u16 bufX[2][64 * DIM];     // 2 x 24576 B
    __shared__ __align__(16) u16 bufO[2][64 * AO_STR];  // 2 x 25600 B  (total 100352 B)

    const int tid  = threadIdx.x;
    const int wv   = tid >> 6;          // 0..11
    const int h    = wv >> 1;           // head 0..5
    const int win  = wv & 1;            // window parity 0..1
    const int lane = tid & 63;
    const int l15  = lane & 15;
    const int g    = lane >> 4;

    // XCD swizzle: dispatch i -> XCD i%8; each XCD gets one full image (196 pair-groups)
    const int b   = blockIdx.x & 7;
    const int grp = blockIdx.x >> 3;    // 0..195 -> pairs {2grp, 2grp+1}

    const float* xb = x   + (size_t)b * DIM*IMG*IMG;
    float*       ob = out + (size_t)b * DIM*IMG*IMG;

    // gather thread geometry (fixed)
    const int gwin  = (tid >= 384) ? 1 : 0;
    const int tl    = tid - gwin*384;
    const int gq    = tl & 15;
    const int gtrow = gq >> 1;
    const int gtcol = (gq & 1) * 4;
    const int gt0   = gtrow*8 + gtcol;
    const int gc0   = tl >> 4;          // 0..23

    #pragma unroll 1
    for (int u = 0; u < PPB; ++u) {
        const int rm = grp*PPB + u;     // pair index -> windows {2rm, 2rm+1}

        // ---------- phase 0: gather (float4); 384-thread half per window; 2 rolled halves ----------
        {
            const int widx = rm*2 + gwin;
            const int gwi  = widx / NWIN, gwj = widx - gwi*NWIN;
            int ghh = gwi*8 + gtrow + 4; if (ghh >= IMG) ghh -= IMG;   // roll(-4) folded in
            int gww = gwj*8 + gtcol + 4; if (gww >= IMG) gww -= IMG;   // 16B vec never straddles wrap
            const size_t pixoff = (size_t)ghh*IMG + gww;
            u16* bXg = bufX[gwin];

            #pragma unroll 1
            for (int half = 0; half < 2; ++half) {
                v4f buf[4];
                #pragma unroll
                for (int it = 0; it < 4; ++it)
                    buf[it] = *(const v4f*)(xb + (size_t)(gc0 + (half*4 + it)*24)*(IMG*IMG) + pixoff);
                #pragma unroll
                for (int it = 0; it < 4; ++it) {
                    int c = gc0 + (half*4 + it)*24;
                    #pragma unroll
                    for (int i2 = 0; i2 < 4; ++i2) {
                        int tok = gt0 + i2;
                        bXg[tok*DIM + (c ^ SWZ(tok))] = f2bf(buf[it][i2]);
                    }
                }
            }
        }
        __syncthreads();   // B1: both X tiles published

        // compute-side window coords
        const int widx = rm*2 + win;
        const int wi = widx / NWIN, wj = widx - wi*NWIN;
        u16* bX = bufX[win];
        u16* bO = bufO[win];

        // ---------- phase 1a: V GEMM (r5-proven); kk rolled ----------
        v8s vfr[2][2];   // PV A-operands, slot (g,j) <-> key 16*(2kk+(j>>2))+4g+(j&3)
        {
            v4f vacc[4][2];
            #pragma unroll
            for (int mt = 0; mt < 4; ++mt)
                #pragma unroll
                for (int ntl = 0; ntl < 2; ++ntl)
                    vacc[mt][ntl] = (v4f){0.f,0.f,0.f,0.f};
            #pragma unroll 1
            for (int kk = 0; kk < 6; ++kk) {
                v8s xfr[4];
                #pragma unroll
                for (int mt = 0; mt < 4; ++mt) {
                    int tok = mt*16 + l15;
                    xfr[mt] = *(const v8s*)&bX[tok*DIM + ((kk*32 + g*8) ^ SWZ(tok))];
                }
                v8s wvf[2];
                #pragma unroll
                for (int ntl = 0; ntl < 2; ++ntl)
                    wvf[ntl] = *(const v8s*)(qw + (size_t)(2*DIM + h*32 + ntl*16 + l15)*DIM + kk*32 + g*8);
                __builtin_amdgcn_s_setprio(1);
                #pragma unroll
                for (int ntl = 0; ntl < 2; ++ntl)
                    #pragma unroll
                    for (int mt = 0; mt < 4; ++mt)
                        vacc[mt][ntl] = __builtin_amdgcn_mfma_f32_16x16x32_bf16(xfr[mt], wvf[ntl], vacc[mt][ntl], 0, 0, 0);
                __builtin_amdgcn_s_setprio(0);
            }
            #pragma unroll
            for (int ntl = 0; ntl < 2; ++ntl) {
                const float bv = qb2[2*DIM + h*32 + ntl*16 + l15];
                #pragma unroll
                for (int kk = 0; kk < 2; ++kk) {
                    union { v8s v; uint32_t d[4]; } uu;
                    uu.d[0] = pk2(vacc[2*kk  ][ntl][0]+bv, vacc[2*kk  ][ntl][1]+bv);
                    uu.d[1] = pk2(vacc[2*kk  ][ntl][2]+bv, vacc[2*kk  ][ntl][3]+bv);
                    uu.d[2] = pk2(vacc[2*kk+1][ntl][0]+bv, vacc[2*kk+1][ntl][1]+bv);
                    uu.d[3] = pk2(vacc[2*kk+1][ntl][2]+bv, vacc[2*kk+1][ntl][3]+bv);
                    vfr[kk][ntl] = uu.v;
                }
            }
        }

        // ---------- phase 1bc: fused Q^T + K^T GEMM (r8/r14-proven); kk rolled ----------
        v8s qfr[4], kfr[4];
        {
            v4f qacc[2][4], kacc[2][4];
            #pragma unroll
            for (int ntl = 0; ntl < 2; ++ntl)
                #pragma unroll
                for (int qt = 0; qt < 4; ++qt) {
                    qacc[ntl][qt] = (v4f){0.f,0.f,0.f,0.f};
                    kacc[ntl][qt] = (v4f){0.f,0.f,0.f,0.f};
                }
            #pragma unroll 1
            for (int kk = 0; kk < 6; ++kk) {
                v8s xfr[4];
                #pragma unroll
                for (int qt = 0; qt < 4; ++qt) {
                    int tok = qt*16 + l15;
                    xfr[qt] = *(const v8s*)&bX[tok*DIM + ((kk*32 + g*8) ^ SWZ(tok))];
                }
                v8s wq[2], wk[2];
                #pragma unroll
                for (int ntl = 0; ntl < 2; ++ntl) {
                    wq[ntl] = *(const v8s*)(qw + (size_t)(h*32 + ntl*16 + l15)*DIM + kk*32 + g*8);
                    wk[ntl] = *(const v8s*)(qw + (size_t)(DIM + h*32 + ntl*16 + l15)*DIM + kk*32 + g*8);
                }
                __builtin_amdgcn_s_setprio(1);
                #pragma unroll
                for (int ntl = 0; ntl < 2; ++ntl)
                    #pragma unroll
                    for (int qt = 0; qt < 4; ++qt) {
                        qacc[ntl][qt] = __builtin_amdgcn_mfma_f32_16x16x32_bf16(wq[ntl], xfr[qt], qacc[ntl][qt], 0, 0, 0);
                        kacc[ntl][qt] = __builtin_amdgcn_mfma_f32_16x16x32_bf16(wk[ntl], xfr[qt], kacc[ntl][qt], 0, 0, 0);
                    }
                __builtin_amdgcn_s_setprio(0);
            }
            v4f bqv[2], bkv[2];
            #pragma unroll
            for (int ntl = 0; ntl < 2; ++ntl) {
                bqv[ntl] = *(const v4f*)&qb2[h*32 + ntl*16 + 4*g];
                bkv[ntl] = *(const v4f*)&qb2[DIM + h*32 + ntl*16 + 4*g];
            }
            #pragma unroll
            for (int qt = 0; qt < 4; ++qt) {
                union { v8s v; uint32_t d[4]; } uq, uk;
                uq.d[0] = pk2(qacc[0][qt][0]+bqv[0][0], qacc[0][qt][1]+bqv[0][1]);
                uq.d[1] = pk2(qacc[0][qt][2]+bqv[0][2], qacc[0][qt][3]+bqv[0][3]);
                uq.d[2] = pk2(qacc[1][qt][0]+bqv[1][0], qacc[1][qt][1]+bqv[1][1]);
                uq.d[3] = pk2(qacc[1][qt][2]+bqv[1][2], qacc[1][qt][3]+bqv[1][3]);
                uk.d[0] = pk2(kacc[0][qt][0]+bkv[0][0], kacc[0][qt][1]+bkv[0][1]);
                uk.d[1] = pk2(kacc[0][qt][2]+bkv[0][2], kacc[0][qt][3]+bkv[0][3]);
                uk.d[2] = pk2(kacc[1][qt][0]+bkv[1][0], kacc[1][qt][1]+bkv[1][1]);
                uk.d[3] = pk2(kacc[1][qt][2]+bkv[1][2], kacc[1][qt][3]+bkv[1][3]);
                qfr[qt] = uq.v;
                kfr[qt] = uk.v;
            }
        }

        // ---------- phase 2: attention; per-qt softmax -> pack -> PV ----------
        v4f oT[2][4];   // [ntl][qt]: O[query=16qt+l15][d=16ntl+4g+r]
        #pragma unroll
        for (int ntl = 0; ntl < 2; ++ntl)
            #pragma unroll
            for (int qt = 0; qt < 4; ++qt)
                oT[ntl][qt] = (v4f){0.f,0.f,0.f,0.f};
        const float* bt = biasT + h*4096;
        #pragma unroll
        for (int qt = 0; qt < 4; ++qt) {
            v4f bb[4];
            #pragma unroll
            for (int kt = 0; kt < 4; ++kt)
                bb[kt] = *(const v4f*)&bt[(qt*16 + l15)*64 + kt*16 + 4*g];
            v4f sq[4];
            __builtin_amdgcn_s_setprio(1);
            #pragma unroll
            for (int kt = 0; kt < 4; ++kt)
                sq[kt] = __builtin_amdgcn_mfma_f32_16x16x32_bf16(kfr[kt], qfr[qt],
                             (v4f){0.f,0.f,0.f,0.f}, 0, 0, 0);
            __builtin_amdgcn_s_setprio(0);
            #pragma unroll
            for (int kt = 0; kt < 4; ++kt) sq[kt] += bb[kt];
            // tree max (per-kt max4, then combine — ILP-friendly, v_max3-fusable)
            float m0 = fmaxf(fmaxf(sq[0][0], sq[0][1]), fmaxf(sq[0][2], sq[0][3]));
            float m1 = fmaxf(fmaxf(sq[1][0], sq[1][1]), fmaxf(sq[1][2], sq[1][3]));
            float m2 = fmaxf(fmaxf(sq[2][0], sq[2][1]), fmaxf(sq[2][2], sq[2][3]));
            float m3 = fmaxf(fmaxf(sq[3][0], sq[3][1]), fmaxf(sq[3][2], sq[3][3]));
            float mx = fmaxf(fmaxf(m0, m1), fmaxf(m2, m3));
            mx = fmaxf(mx, __shfl_xor(mx, 16));
            mx = fmaxf(mx, __shfl_xor(mx, 32));
            float s0 = 0.f, s1 = 0.f;
            #pragma unroll
            for (int kt = 0; kt < 4; ++kt)
                #pragma unroll
                for (int r = 0; r < 4; ++r) {
                    float e = __expf(sq[kt][r] - mx);
                    sq[kt][r] = e;
                    if (kt < 2) s0 += e; else s1 += e;
                }
            float sum = s0 + s1;
            sum += __shfl_xor(sum, 16);
            sum += __shfl_xor(sum, 32);
            float inv = 1.f / sum;
            #pragma unroll
            for (int kt = 0; kt < 4; ++kt)
                #pragma unroll
                for (int r = 0; r < 4; ++r) sq[kt][r] *= inv;

            union { v8s v; uint32_t d[4]; } p0, p1;
            p0.d[0] = pk2(sq[0][0], sq[0][1]); p0.d[1] = pk2(sq[0][2], sq[0][3]);
            p0.d[2] = pk2(sq[1][0], sq[1][1]); p0.d[3] = pk2(sq[1][2], sq[1][3]);
            p1.d[0] = pk2(sq[2][0], sq[2][1]); p1.d[1] = pk2(sq[2][2], sq[2][3]);
            p1.d[2] = pk2(sq[3][0], sq[3][1]); p1.d[3] = pk2(sq[3][2], sq[3][3]);
            __builtin_amdgcn_s_setprio(1);
            #pragma unroll
            for (int ntl = 0; ntl < 2; ++ntl) {
                oT[ntl][qt] = __builtin_amdgcn_mfma_f32_16x16x32_bf16(vfr[0][ntl], p0.v, oT[ntl][qt], 0, 0, 0);
                oT[ntl][qt] = __builtin_amdgcn_mfma_f32_16x16x32_bf16(vfr[1][ntl], p1.v, oT[ntl][qt], 0, 0, 0);
            }
            __builtin_amdgcn_s_setprio(0);
        }

        // attn_out -> bO [64][AO_STR], b64 stores
        #pragma unroll
        for (int qt = 0; qt < 4; ++qt)
            #pragma unroll
            for (int ntl = 0; ntl < 2; ++ntl) {
                v2u o;
                o.x = pk2(oT[ntl][qt][0], oT[ntl][qt][1]);
                o.y = pk2(oT[ntl][qt][2], oT[ntl][qt][3]);
                *(v2u*)&bO[(qt*16 + l15)*AO_STR + h*32 + ntl*16 + 4*g] = o;
            }
        __syncthreads();   // B2: both AO tiles complete; bufX dead

        // ---------- phase 3: transposed proj GEMM (kk rolled) + direct register scatter ----------
        v4f pacc[2][4];
        #pragma unroll
        for (int ntl = 0; ntl < 2; ++ntl)
            #pragma unroll
            for (int qt = 0; qt < 4; ++qt)
                pacc[ntl][qt] = (v4f){0.f,0.f,0.f,0.f};
        #pragma unroll 1
        for (int kk = 0; kk < 6; ++kk) {
            v8s aofr[4];
            #pragma unroll
            for (int qt = 0; qt < 4; ++qt)
                aofr[qt] = *(const v8s*)&bO[(qt*16 + l15)*AO_STR + kk*32 + g*8];
            v8s pwfr[2];
            #pragma unroll
            for (int ntl = 0; ntl < 2; ++ntl)
                pwfr[ntl] = *(const v8s*)(pw + (size_t)(h*32 + ntl*16 + l15)*DIM + kk*32 + g*8);
            __builtin_amdgcn_s_setprio(1);
            #pragma unroll
            for (int ntl = 0; ntl < 2; ++ntl)
                #pragma unroll
                for (int qt = 0; qt < 4; ++qt)
                    pacc[ntl][qt] = __builtin_amdgcn_mfma_f32_16x16x32_bf16(pwfr[ntl], aofr[qt], pacc[ntl][qt], 0, 0, 0);
            __builtin_amdgcn_s_setprio(0);
        }
        float pb[2][4];
        #pragma unroll
        for (int ntl = 0; ntl < 2; ++ntl) {
            v4f pbv = *(const v4f*)&proj_b[h*32 + ntl*16 + 4*g];
            #pragma unroll
            for (int r = 0; r < 4; ++r) pb[ntl][r] = pbv[r];
        }

        #pragma unroll
        for (int qt = 0; qt < 4; ++qt) {
            const int strow = 2*qt + (l15 >> 3);
            const int stcol = l15 & 7;
            int hh = wi*8 + strow + 4; if (hh >= IMG) hh -= IMG;
            int ww = wj*8 + stcol + 4; if (ww >= IMG) ww -= IMG;
            const size_t pix = (size_t)hh*IMG + ww;
            #pragma unroll
            for (int ntl = 0; ntl < 2; ++ntl)
                #pragma unroll
                for (int r = 0; r < 4; ++r) {
                    const int c = h*32 + ntl*16 + 4*g + r;
                    ob[(size_t)c*(IMG*IMG) + pix] = pacc[ntl][qt][r] + pb[ntl][r];
                }
        }

        if (u < PPB-1)
            __syncthreads();   // B3: bufO reads done; bufX free for next pair's gather
    }
}

extern "C" void kernel_launch(void* const* d_in, const int* in_sizes, int n_in,
                              void* d_out, int out_size, void* d_ws, size_t ws_size,
                              hipStream_t stream) {
    const float* x        = (const float*)d_in[0];
    const float* qkv_w    = (const float*)d_in[1];
    const float* qkv_b    = (const float*)d_in[2];
    const float* proj_w   = (const float*)d_in[3];
    const float* proj_b   = (const float*)d_in[4];
    const float* rel_bias = (const float*)d_in[5];
    const int*   rel_idx  = (const int*)d_in[6];

    u16*   qw_bf  = (u16*)d_ws;                         // 221184 B
    u16*   pw_bf  = (u16*)((char*)d_ws + 221184);       //  73728 B
    float* qb2    = (float*)((char*)d_ws + 294912);     //   2304 B
    float* biasT  = (float*)((char*)d_ws + 297216);     //  98304 B
    float* out    = (float*)d_out;

    hipLaunchKernelGGL(prep_kernel, dim3(432), dim3(256), 0, stream,
                       qkv_w, qkv_b, proj_w, rel_bias, rel_idx, qw_bf, pw_bf, qb2, biasT);
    hipLaunchKernelGGL(winattn_kernel, dim3(NB * (NWIN*NWIN/2/PPB)), dim3(768), 0, stream,
                       x, proj_b, qw_bf, pw_bf, qb2, biasT, out);
}

// Round 19
// 492.099 us; speedup vs baseline: 1.5549x; 1.5549x over previous
//
#include <hip/hip_runtime.h>
#include <hip/hip_bf16.h>
#include <stdint.h>

typedef unsigned short u16;
typedef short v8s __attribute__((ext_vector_type(8)));
typedef float v4f __attribute__((ext_vector_type(4)));
typedef uint32_t v2u __attribute__((ext_vector_type(2)));

#define DIM 192
#define NH 6
#define IMG 224
#define NWIN 28
#define NB 8
#define SCALE 0.17677669529663687f
#define AO_STR 200   // bf16 stride for attn_out tile

// X-tile swizzle (r9-proven): bijective per token, halves gather-store conflicts
#define SWZ(tok) ((((tok) & 7) ^ ((tok) >> 3)) << 3)

__device__ __forceinline__ u16 f2bf(float f) {
    union { __hip_bfloat16 b; u16 u; } c; c.b = __float2bfloat16(f); return c.u;
}
__device__ __forceinline__ uint32_t pk2(float lo, float hi) {
    union { __hip_bfloat162 b; uint32_t u; } c;
    c.b = __float22bfloat162_rn(make_float2(lo, hi));
    return c.u;
}

// ---- prep: bf16 weights (SCALE folded into q rows), scaled bias, expanded bias table ----
__global__ void prep_kernel(const float* __restrict__ qkv_w,
                            const float* __restrict__ qkv_b,
                            const float* __restrict__ proj_w,
                            const float* __restrict__ rel_bias,
                            const int* __restrict__ rel_idx,
                            u16* __restrict__ qw, u16* __restrict__ pw,
                            float* __restrict__ qb2, float* __restrict__ biasT) {
    int i = blockIdx.x * 256 + threadIdx.x;
    if (i < 3*DIM*DIM) {
        float s = (i < DIM*DIM) ? SCALE : 1.f;
        qw[i] = f2bf(qkv_w[i] * s);
    }
    if (i < DIM*DIM) pw[i] = f2bf(proj_w[i]);
    if (i < 3*DIM)   qb2[i] = qkv_b[i] * (i < DIM ? SCALE : 1.f);
    if (i < NH*64*64) {
        int h   = i >> 12;          // biasT[h][query][key], key minor
        int qk2 = i & 4095;
        biasT[i] = rel_bias[rel_idx[qk2]*NH + h];
    }
}

// ---- fused window attention: one block = 2 adjacent windows x 6 heads = 12 waves ----
// ---- r17 structure (single pass, rolled GEMM loops) + tree-max softmax ----
__global__ __launch_bounds__(768, 3) void winattn_kernel(
    const float* __restrict__ x,
    const float* __restrict__ proj_b,
    const u16* __restrict__ qw,
    const u16* __restrict__ pw,
    const float* __restrict__ qb2,
    const float* __restrict__ biasT,
    float* __restrict__ out)
{
    __shared__ __align__(16) u16 bufX[2][64 * DIM];     // 2 x 24576 B
    __shared__ __align__(16) u16 bufO[2][64 * AO_STR];  // 2 x 25600 B  (total 100352 B)

    const int tid  = threadIdx.x;
    const int wv   = tid >> 6;          // 0..11
    const int h    = wv >> 1;           // head 0..5
    const int win  = wv & 1;            // window parity 0..1
    const int lane = tid & 63;
    const int l15  = lane & 15;
    const int g    = lane >> 4;

    // XCD swizzle: dispatch i -> XCD i%8; each XCD gets one full image (392 pairs)
    const int b  = blockIdx.x & 7;
    const int rm = blockIdx.x >> 3;     // 0..391 -> windows {2rm, 2rm+1} (wj-adjacent)

    const float* xb = x   + (size_t)b * DIM*IMG*IMG;
    float*       ob = out + (size_t)b * DIM*IMG*IMG;

    // ---------- phase 0: gather (float4); 384-thread half per window; 2 rolled halves ----------
    {
        const int gwin = (tid >= 384) ? 1 : 0;
        const int tl   = tid - gwin*384;
        const int widx = rm*2 + gwin;
        const int gwi  = widx / NWIN, gwj = widx - gwi*NWIN;
        const int qq   = tl & 15;
        const int trow = qq >> 1;
        const int tcol = (qq & 1) * 4;
        const int t0   = trow*8 + tcol;
        const int c0   = tl >> 4;           // 0..23
        int ghh = gwi*8 + trow + 4; if (ghh >= IMG) ghh -= IMG;   // roll(-4) folded in
        int gww = gwj*8 + tcol + 4; if (gww >= IMG) gww -= IMG;   // 16B vec never straddles wrap
        const size_t pixoff = (size_t)ghh*IMG + gww;
        u16* bX = bufX[gwin];

        #pragma unroll 1
        for (int half = 0; half < 2; ++half) {
            v4f buf[4];
            #pragma unroll
            for (int it = 0; it < 4; ++it)
                buf[it] = *(const v4f*)(xb + (size_t)(c0 + (half*4 + it)*24)*(IMG*IMG) + pixoff);
            #pragma unroll
            for (int it = 0; it < 4; ++it) {
                int c = c0 + (half*4 + it)*24;
                #pragma unroll
                for (int i2 = 0; i2 < 4; ++i2) {
                    int tok = t0 + i2;
                    bX[tok*DIM + (c ^ SWZ(tok))] = f2bf(buf[it][i2]);
                }
            }
        }
    }
    __syncthreads();   // B1: both X tiles published

    // compute-side window coords
    const int widx = rm*2 + win;
    const int wi = widx / NWIN, wj = widx - wi*NWIN;
    u16* bX = bufX[win];
    u16* bO = bufO[win];

    // ---------- phase 1a: V GEMM (r5-proven); kk rolled ----------
    v8s vfr[2][2];   // PV A-operands, slot (g,j) <-> key 16*(2kk+(j>>2))+4g+(j&3)
    {
        v4f vacc[4][2];
        #pragma unroll
        for (int mt = 0; mt < 4; ++mt)
            #pragma unroll
            for (int ntl = 0; ntl < 2; ++ntl)
                vacc[mt][ntl] = (v4f){0.f,0.f,0.f,0.f};
        #pragma unroll 1
        for (int kk = 0; kk < 6; ++kk) {
            v8s xfr[4];
            #pragma unroll
            for (int mt = 0; mt < 4; ++mt) {
                int tok = mt*16 + l15;
                xfr[mt] = *(const v8s*)&bX[tok*DIM + ((kk*32 + g*8) ^ SWZ(tok))];
            }
            v8s wvf[2];
            #pragma unroll
            for (int ntl = 0; ntl < 2; ++ntl)
                wvf[ntl] = *(const v8s*)(qw + (size_t)(2*DIM + h*32 + ntl*16 + l15)*DIM + kk*32 + g*8);
            __builtin_amdgcn_s_setprio(1);
            #pragma unroll
            for (int ntl = 0; ntl < 2; ++ntl)
                #pragma unroll
                for (int mt = 0; mt < 4; ++mt)
                    vacc[mt][ntl] = __builtin_amdgcn_mfma_f32_16x16x32_bf16(xfr[mt], wvf[ntl], vacc[mt][ntl], 0, 0, 0);
            __builtin_amdgcn_s_setprio(0);
        }
        #pragma unroll
        for (int ntl = 0; ntl < 2; ++ntl) {
            const float bv = qb2[2*DIM + h*32 + ntl*16 + l15];
            #pragma unroll
            for (int kk = 0; kk < 2; ++kk) {
                union { v8s v; uint32_t d[4]; } uu;
                uu.d[0] = pk2(vacc[2*kk  ][ntl][0]+bv, vacc[2*kk  ][ntl][1]+bv);
                uu.d[1] = pk2(vacc[2*kk  ][ntl][2]+bv, vacc[2*kk  ][ntl][3]+bv);
                uu.d[2] = pk2(vacc[2*kk+1][ntl][0]+bv, vacc[2*kk+1][ntl][1]+bv);
                uu.d[3] = pk2(vacc[2*kk+1][ntl][2]+bv, vacc[2*kk+1][ntl][3]+bv);
                vfr[kk][ntl] = uu.v;
            }
        }
    }

    // ---------- phase 1bc: fused Q^T + K^T GEMM (r8/r14-proven); kk rolled ----------
    v8s qfr[4], kfr[4];
    {
        v4f qacc[2][4], kacc[2][4];
        #pragma unroll
        for (int ntl = 0; ntl < 2; ++ntl)
            #pragma unroll
            for (int qt = 0; qt < 4; ++qt) {
                qacc[ntl][qt] = (v4f){0.f,0.f,0.f,0.f};
                kacc[ntl][qt] = (v4f){0.f,0.f,0.f,0.f};
            }
        #pragma unroll 1
        for (int kk = 0; kk < 6; ++kk) {
            v8s xfr[4];
            #pragma unroll
            for (int qt = 0; qt < 4; ++qt) {
                int tok = qt*16 + l15;
                xfr[qt] = *(const v8s*)&bX[tok*DIM + ((kk*32 + g*8) ^ SWZ(tok))];
            }
            v8s wq[2], wk[2];
            #pragma unroll
            for (int ntl = 0; ntl < 2; ++ntl) {
                wq[ntl] = *(const v8s*)(qw + (size_t)(h*32 + ntl*16 + l15)*DIM + kk*32 + g*8);
                wk[ntl] = *(const v8s*)(qw + (size_t)(DIM + h*32 + ntl*16 + l15)*DIM + kk*32 + g*8);
            }
            __builtin_amdgcn_s_setprio(1);
            #pragma unroll
            for (int ntl = 0; ntl < 2; ++ntl)
                #pragma unroll
                for (int qt = 0; qt < 4; ++qt) {
                    qacc[ntl][qt] = __builtin_amdgcn_mfma_f32_16x16x32_bf16(wq[ntl], xfr[qt], qacc[ntl][qt], 0, 0, 0);
                    kacc[ntl][qt] = __builtin_amdgcn_mfma_f32_16x16x32_bf16(wk[ntl], xfr[qt], kacc[ntl][qt], 0, 0, 0);
                }
            __builtin_amdgcn_s_setprio(0);
        }
        v4f bqv[2], bkv[2];
        #pragma unroll
        for (int ntl = 0; ntl < 2; ++ntl) {
            bqv[ntl] = *(const v4f*)&qb2[h*32 + ntl*16 + 4*g];
            bkv[ntl] = *(const v4f*)&qb2[DIM + h*32 + ntl*16 + 4*g];
        }
        #pragma unroll
        for (int qt = 0; qt < 4; ++qt) {
            union { v8s v; uint32_t d[4]; } uq, uk;
            uq.d[0] = pk2(qacc[0][qt][0]+bqv[0][0], qacc[0][qt][1]+bqv[0][1]);
            uq.d[1] = pk2(qacc[0][qt][2]+bqv[0][2], qacc[0][qt][3]+bqv[0][3]);
            uq.d[2] = pk2(qacc[1][qt][0]+bqv[1][0], qacc[1][qt][1]+bqv[1][1]);
            uq.d[3] = pk2(qacc[1][qt][2]+bqv[1][2], qacc[1][qt][3]+bqv[1][3]);
            uk.d[0] = pk2(kacc[0][qt][0]+bkv[0][0], kacc[0][qt][1]+bkv[0][1]);
            uk.d[1] = pk2(kacc[0][qt][2]+bkv[0][2], kacc[0][qt][3]+bkv[0][3]);
            uk.d[2] = pk2(kacc[1][qt][0]+bkv[1][0], kacc[1][qt][1]+bkv[1][1]);
            uk.d[3] = pk2(kacc[1][qt][2]+bkv[1][2], kacc[1][qt][3]+bkv[1][3]);
            qfr[qt] = uq.v;
            kfr[qt] = uk.v;
        }
    }

    // ---------- phase 2: attention; per-qt softmax (tree reduce) -> pack -> PV ----------
    v4f oT[2][4];   // [ntl][qt]: O[query=16qt+l15][d=16ntl+4g+r]
    #pragma unroll
    for (int ntl = 0; ntl < 2; ++ntl)
        #pragma unroll
        for (int qt = 0; qt < 4; ++qt)
            oT[ntl][qt] = (v4f){0.f,0.f,0.f,0.f};
    const float* bt = biasT + h*4096;
    #pragma unroll
    for (int qt = 0; qt < 4; ++qt) {
        v4f bb[4];
        #pragma unroll
        for (int kt = 0; kt < 4; ++kt)
            bb[kt] = *(const v4f*)&bt[(qt*16 + l15)*64 + kt*16 + 4*g];
        v4f sq[4];
        __builtin_amdgcn_s_setprio(1);
        #pragma unroll
        for (int kt = 0; kt < 4; ++kt)
            sq[kt] = __builtin_amdgcn_mfma_f32_16x16x32_bf16(kfr[kt], qfr[qt],
                         (v4f){0.f,0.f,0.f,0.f}, 0, 0, 0);
        __builtin_amdgcn_s_setprio(0);
        #pragma unroll
        for (int kt = 0; kt < 4; ++kt) sq[kt] += bb[kt];
        // tree max (per-kt max4, then combine — ILP-friendly, v_max3-fusable)
        float m0 = fmaxf(fmaxf(sq[0][0], sq[0][1]), fmaxf(sq[0][2], sq[0][3]));
        float m1 = fmaxf(fmaxf(sq[1][0], sq[1][1]), fmaxf(sq[1][2], sq[1][3]));
        float m2 = fmaxf(fmaxf(sq[2][0], sq[2][1]), fmaxf(sq[2][2], sq[2][3]));
        float m3 = fmaxf(fmaxf(sq[3][0], sq[3][1]), fmaxf(sq[3][2], sq[3][3]));
        float mx = fmaxf(fmaxf(m0, m1), fmaxf(m2, m3));
        mx = fmaxf(mx, __shfl_xor(mx, 16));
        mx = fmaxf(mx, __shfl_xor(mx, 32));
        float s0 = 0.f, s1 = 0.f;
        #pragma unroll
        for (int kt = 0; kt < 4; ++kt)
            #pragma unroll
            for (int r = 0; r < 4; ++r) {
                float e = __expf(sq[kt][r] - mx);
                sq[kt][r] = e;
                if (kt < 2) s0 += e; else s1 += e;
            }
        float sum = s0 + s1;
        sum += __shfl_xor(sum, 16);
        sum += __shfl_xor(sum, 32);
        float inv = 1.f / sum;
        #pragma unroll
        for (int kt = 0; kt < 4; ++kt)
            #pragma unroll
            for (int r = 0; r < 4; ++r) sq[kt][r] *= inv;

        union { v8s v; uint32_t d[4]; } p0, p1;
        p0.d[0] = pk2(sq[0][0], sq[0][1]); p0.d[1] = pk2(sq[0][2], sq[0][3]);
        p0.d[2] = pk2(sq[1][0], sq[1][1]); p0.d[3] = pk2(sq[1][2], sq[1][3]);
        p1.d[0] = pk2(sq[2][0], sq[2][1]); p1.d[1] = pk2(sq[2][2], sq[2][3]);
        p1.d[2] = pk2(sq[3][0], sq[3][1]); p1.d[3] = pk2(sq[3][2], sq[3][3]);
        __builtin_amdgcn_s_setprio(1);
        #pragma unroll
        for (int ntl = 0; ntl < 2; ++ntl) {
            oT[ntl][qt] = __builtin_amdgcn_mfma_f32_16x16x32_bf16(vfr[0][ntl], p0.v, oT[ntl][qt], 0, 0, 0);
            oT[ntl][qt] = __builtin_amdgcn_mfma_f32_16x16x32_bf16(vfr[1][ntl], p1.v, oT[ntl][qt], 0, 0, 0);
        }
        __builtin_amdgcn_s_setprio(0);
    }

    // attn_out -> bO [64][AO_STR], b64 stores
    #pragma unroll
    for (int qt = 0; qt < 4; ++qt)
        #pragma unroll
        for (int ntl = 0; ntl < 2; ++ntl) {
            v2u o;
            o.x = pk2(oT[ntl][qt][0], oT[ntl][qt][1]);
            o.y = pk2(oT[ntl][qt][2], oT[ntl][qt][3]);
            *(v2u*)&bO[(qt*16 + l15)*AO_STR + h*32 + ntl*16 + 4*g] = o;
        }
    __syncthreads();   // B2: both AO tiles complete

    // ---------- phase 3: transposed proj GEMM (kk rolled) + direct register scatter ----------
    v4f pacc[2][4];
    #pragma unroll
    for (int ntl = 0; ntl < 2; ++ntl)
        #pragma unroll
        for (int qt = 0; qt < 4; ++qt)
            pacc[ntl][qt] = (v4f){0.f,0.f,0.f,0.f};
    #pragma unroll 1
    for (int kk = 0; kk < 6; ++kk) {
        v8s aofr[4];
        #pragma unroll
        for (int qt = 0; qt < 4; ++qt)
            aofr[qt] = *(const v8s*)&bO[(qt*16 + l15)*AO_STR + kk*32 + g*8];
        v8s pwfr[2];
        #pragma unroll
        for (int ntl = 0; ntl < 2; ++ntl)
            pwfr[ntl] = *(const v8s*)(pw + (size_t)(h*32 + ntl*16 + l15)*DIM + kk*32 + g*8);
        __builtin_amdgcn_s_setprio(1);
        #pragma unroll
        for (int ntl = 0; ntl < 2; ++ntl)
            #pragma unroll
            for (int qt = 0; qt < 4; ++qt)
                pacc[ntl][qt] = __builtin_amdgcn_mfma_f32_16x16x32_bf16(pwfr[ntl], aofr[qt], pacc[ntl][qt], 0, 0, 0);
        __builtin_amdgcn_s_setprio(0);
    }
    float pb[2][4];
    #pragma unroll
    for (int ntl = 0; ntl < 2; ++ntl) {
        v4f pbv = *(const v4f*)&proj_b[h*32 + ntl*16 + 4*g];
        #pragma unroll
        for (int r = 0; r < 4; ++r) pb[ntl][r] = pbv[r];
    }

    #pragma unroll
    for (int qt = 0; qt < 4; ++qt) {
        const int strow = 2*qt + (l15 >> 3);
        const int stcol = l15 & 7;
        int hh = wi*8 + strow + 4; if (hh >= IMG) hh -= IMG;
        int ww = wj*8 + stcol + 4; if (ww >= IMG) ww -= IMG;
        const size_t pix = (size_t)hh*IMG + ww;
        #pragma unroll
        for (int ntl = 0; ntl < 2; ++ntl)
            #pragma unroll
            for (int r = 0; r < 4; ++r) {
                const int c = h*32 + ntl*16 + 4*g + r;
                ob[(size_t)c*(IMG*IMG) + pix] = pacc[ntl][qt][r] + pb[ntl][r];
            }
    }
}

extern "C" void kernel_launch(void* const* d_in, const int* in_sizes, int n_in,
                              void* d_out, int out_size, void* d_ws, size_t ws_size,
                              hipStream_t stream) {
    const float* x        = (const float*)d_in[0];
    const float* qkv_w    = (const float*)d_in[1];
    const float* qkv_b    = (const float*)d_in[2];
    const float* proj_w   = (const float*)d_in[3];
    const float* proj_b   = (const float*)d_in[4];
    const float* rel_bias = (const float*)d_in[5];
    const int*   rel_idx  = (const int*)d_in[6];

    u16*   qw_bf  = (u16*)d_ws;                         // 221184 B
    u16*   pw_bf  = (u16*)((char*)d_ws + 221184);       //  73728 B
    float* qb2    = (float*)((char*)d_ws + 294912);     //   2304 B
    float* biasT  = (float*)((char*)d_ws + 297216);     //  98304 B
    float* out    = (float*)d_out;

    hipLaunchKernelGGL(prep_kernel, dim3(432), dim3(256), 0, stream,
                       qkv_w, qkv_b, proj_w, rel_bias, rel_idx, qw_bf, pw_bf, qb2, biasT);
    hipLaunchKernelGGL(winattn_kernel, dim3(NB * (NWIN*NWIN/2)), dim3(768), 0, stream,
                       x, proj_b, qw_bf, pw_bf, qb2, biasT, out);
}

// Round 20
// 490.551 us; speedup vs baseline: 1.5598x; 1.0032x over previous
//
#include <hip/hip_runtime.h>
#include <hip/hip_bf16.h>
#include <stdint.h>

typedef unsigned short u16;
typedef short v8s __attribute__((ext_vector_type(8)));
typedef float v4f __attribute__((ext_vector_type(4)));
typedef uint32_t v2u __attribute__((ext_vector_type(2)));

#define DIM 192
#define NH 6
#define IMG 224
#define NWIN 28
#define NB 8
#define SCALE 0.17677669529663687f
#define AO_STR 200   // bf16 stride for attn_out tile

// X-tile swizzle (r9-proven): bijective per token, halves gather-store conflicts
#define SWZ(tok) ((((tok) & 7) ^ ((tok) >> 3)) << 3)

__device__ __forceinline__ u16 f2bf(float f) {
    union { __hip_bfloat16 b; u16 u; } c; c.b = __float2bfloat16(f); return c.u;
}
__device__ __forceinline__ uint32_t pk2(float lo, float hi) {
    union { __hip_bfloat162 b; uint32_t u; } c;
    c.b = __float22bfloat162_rn(make_float2(lo, hi));
    return c.u;
}

// ---- prep: bf16 weights (SCALE folded into q rows), scaled bias, expanded bias table ----
__global__ void prep_kernel(const float* __restrict__ qkv_w,
                            const float* __restrict__ qkv_b,
                            const float* __restrict__ proj_w,
                            const float* __restrict__ rel_bias,
                            const int* __restrict__ rel_idx,
                            u16* __restrict__ qw, u16* __restrict__ pw,
                            float* __restrict__ qb2, float* __restrict__ biasT) {
    int i = blockIdx.x * 256 + threadIdx.x;
    if (i < 3*DIM*DIM) {
        float s = (i < DIM*DIM) ? SCALE : 1.f;
        qw[i] = f2bf(qkv_w[i] * s);
    }
    if (i < DIM*DIM) pw[i] = f2bf(proj_w[i]);
    if (i < 3*DIM)   qb2[i] = qkv_b[i] * (i < DIM ? SCALE : 1.f);
    if (i < NH*64*64) {
        int h   = i >> 12;          // biasT[h][query][key], key minor
        int qk2 = i & 4095;
        biasT[i] = rel_bias[rel_idx[qk2]*NH + h];
    }
}

// ---- fused window attention: one block = 2 adjacent windows x 6 heads = 12 waves ----
// ---- r19 structure; biases folded into MFMA accumulator INIT (C-in), epilogue adds gone ----
__global__ __launch_bounds__(768, 3) void winattn_kernel(
    const float* __restrict__ x,
    const float* __restrict__ proj_b,
    const u16* __restrict__ qw,
    const u16* __restrict__ pw,
    const float* __restrict__ qb2,
    const float* __restrict__ biasT,
    float* __restrict__ out)
{
    __shared__ __align__(16) u16 bufX[2][64 * DIM];     // 2 x 24576 B
    __shared__ __align__(16) u16 bufO[2][64 * AO_STR];  // 2 x 25600 B  (total 100352 B)

    const int tid  = threadIdx.x;
    const int wv   = tid >> 6;          // 0..11
    const int h    = wv >> 1;           // head 0..5
    const int win  = wv & 1;            // window parity 0..1
    const int lane = tid & 63;
    const int l15  = lane & 15;
    const int g    = lane >> 4;

    // XCD swizzle: dispatch i -> XCD i%8; each XCD gets one full image (392 pairs)
    const int b  = blockIdx.x & 7;
    const int rm = blockIdx.x >> 3;     // 0..391 -> windows {2rm, 2rm+1} (wj-adjacent)

    const float* xb = x   + (size_t)b * DIM*IMG*IMG;
    float*       ob = out + (size_t)b * DIM*IMG*IMG;

    // ---------- phase 0: gather (float4); 384-thread half per window; 2 rolled halves ----------
    {
        const int gwin = (tid >= 384) ? 1 : 0;
        const int tl   = tid - gwin*384;
        const int widx = rm*2 + gwin;
        const int gwi  = widx / NWIN, gwj = widx - gwi*NWIN;
        const int qq   = tl & 15;
        const int trow = qq >> 1;
        const int tcol = (qq & 1) * 4;
        const int t0   = trow*8 + tcol;
        const int c0   = tl >> 4;           // 0..23
        int ghh = gwi*8 + trow + 4; if (ghh >= IMG) ghh -= IMG;   // roll(-4) folded in
        int gww = gwj*8 + tcol + 4; if (gww >= IMG) gww -= IMG;   // 16B vec never straddles wrap
        const size_t pixoff = (size_t)ghh*IMG + gww;
        u16* bX = bufX[gwin];

        #pragma unroll 1
        for (int half = 0; half < 2; ++half) {
            v4f buf[4];
            #pragma unroll
            for (int it = 0; it < 4; ++it)
                buf[it] = *(const v4f*)(xb + (size_t)(c0 + (half*4 + it)*24)*(IMG*IMG) + pixoff);
            #pragma unroll
            for (int it = 0; it < 4; ++it) {
                int c = c0 + (half*4 + it)*24;
                #pragma unroll
                for (int i2 = 0; i2 < 4; ++i2) {
                    int tok = t0 + i2;
                    bX[tok*DIM + (c ^ SWZ(tok))] = f2bf(buf[it][i2]);
                }
            }
        }
    }
    __syncthreads();   // B1: both X tiles published

    // compute-side window coords
    const int widx = rm*2 + win;
    const int wi = widx / NWIN, wj = widx - wi*NWIN;
    u16* bX = bufX[win];
    u16* bO = bufO[win];

    // ---------- phase 1a: V GEMM (r5-proven); bias as accumulator init; kk rolled ----------
    v8s vfr[2][2];   // PV A-operands, slot (g,j) <-> key 16*(2kk+(j>>2))+4g+(j&3)
    {
        float bvv[2];
        #pragma unroll
        for (int ntl = 0; ntl < 2; ++ntl)
            bvv[ntl] = qb2[2*DIM + h*32 + ntl*16 + l15];
        v4f vacc[4][2];
        #pragma unroll
        for (int mt = 0; mt < 4; ++mt)
            #pragma unroll
            for (int ntl = 0; ntl < 2; ++ntl)
                vacc[mt][ntl] = (v4f){bvv[ntl], bvv[ntl], bvv[ntl], bvv[ntl]};
        #pragma unroll 1
        for (int kk = 0; kk < 6; ++kk) {
            v8s xfr[4];
            #pragma unroll
            for (int mt = 0; mt < 4; ++mt) {
                int tok = mt*16 + l15;
                xfr[mt] = *(const v8s*)&bX[tok*DIM + ((kk*32 + g*8) ^ SWZ(tok))];
            }
            v8s wvf[2];
            #pragma unroll
            for (int ntl = 0; ntl < 2; ++ntl)
                wvf[ntl] = *(const v8s*)(qw + (size_t)(2*DIM + h*32 + ntl*16 + l15)*DIM + kk*32 + g*8);
            __builtin_amdgcn_s_setprio(1);
            #pragma unroll
            for (int ntl = 0; ntl < 2; ++ntl)
                #pragma unroll
                for (int mt = 0; mt < 4; ++mt)
                    vacc[mt][ntl] = __builtin_amdgcn_mfma_f32_16x16x32_bf16(xfr[mt], wvf[ntl], vacc[mt][ntl], 0, 0, 0);
            __builtin_amdgcn_s_setprio(0);
        }
        #pragma unroll
        for (int ntl = 0; ntl < 2; ++ntl) {
            #pragma unroll
            for (int kk = 0; kk < 2; ++kk) {
                union { v8s v; uint32_t d[4]; } uu;
                uu.d[0] = pk2(vacc[2*kk  ][ntl][0], vacc[2*kk  ][ntl][1]);
                uu.d[1] = pk2(vacc[2*kk  ][ntl][2], vacc[2*kk  ][ntl][3]);
                uu.d[2] = pk2(vacc[2*kk+1][ntl][0], vacc[2*kk+1][ntl][1]);
                uu.d[3] = pk2(vacc[2*kk+1][ntl][2], vacc[2*kk+1][ntl][3]);
                vfr[kk][ntl] = uu.v;
            }
        }
    }

    // ---------- phase 1bc: fused Q^T + K^T GEMM (r8/r14-proven); bias as acc init; kk rolled ----------
    v8s qfr[4], kfr[4];
    {
        v4f bqv[2], bkv[2];
        #pragma unroll
        for (int ntl = 0; ntl < 2; ++ntl) {
            bqv[ntl] = *(const v4f*)&qb2[h*32 + ntl*16 + 4*g];
            bkv[ntl] = *(const v4f*)&qb2[DIM + h*32 + ntl*16 + 4*g];
        }
        v4f qacc[2][4], kacc[2][4];
        #pragma unroll
        for (int ntl = 0; ntl < 2; ++ntl)
            #pragma unroll
            for (int qt = 0; qt < 4; ++qt) {
                qacc[ntl][qt] = bqv[ntl];
                kacc[ntl][qt] = bkv[ntl];
            }
        #pragma unroll 1
        for (int kk = 0; kk < 6; ++kk) {
            v8s xfr[4];
            #pragma unroll
            for (int qt = 0; qt < 4; ++qt) {
                int tok = qt*16 + l15;
                xfr[qt] = *(const v8s*)&bX[tok*DIM + ((kk*32 + g*8) ^ SWZ(tok))];
            }
            v8s wq[2], wk[2];
            #pragma unroll
            for (int ntl = 0; ntl < 2; ++ntl) {
                wq[ntl] = *(const v8s*)(qw + (size_t)(h*32 + ntl*16 + l15)*DIM + kk*32 + g*8);
                wk[ntl] = *(const v8s*)(qw + (size_t)(DIM + h*32 + ntl*16 + l15)*DIM + kk*32 + g*8);
            }
            __builtin_amdgcn_s_setprio(1);
            #pragma unroll
            for (int ntl = 0; ntl < 2; ++ntl)
                #pragma unroll
                for (int qt = 0; qt < 4; ++qt) {
                    qacc[ntl][qt] = __builtin_amdgcn_mfma_f32_16x16x32_bf16(wq[ntl], xfr[qt], qacc[ntl][qt], 0, 0, 0);
                    kacc[ntl][qt] = __builtin_amdgcn_mfma_f32_16x16x32_bf16(wk[ntl], xfr[qt], kacc[ntl][qt], 0, 0, 0);
                }
            __builtin_amdgcn_s_setprio(0);
        }
        #pragma unroll
        for (int qt = 0; qt < 4; ++qt) {
            union { v8s v; uint32_t d[4]; } uq, uk;
            uq.d[0] = pk2(qacc[0][qt][0], qacc[0][qt][1]);
            uq.d[1] = pk2(qacc[0][qt][2], qacc[0][qt][3]);
            uq.d[2] = pk2(qacc[1][qt][0], qacc[1][qt][1]);
            uq.d[3] = pk2(qacc[1][qt][2], qacc[1][qt][3]);
            uk.d[0] = pk2(kacc[0][qt][0], kacc[0][qt][1]);
            uk.d[1] = pk2(kacc[0][qt][2], kacc[0][qt][3]);
            uk.d[2] = pk2(kacc[1][qt][0], kacc[1][qt][1]);
            uk.d[3] = pk2(kacc[1][qt][2], kacc[1][qt][3]);
            qfr[qt] = uq.v;
            kfr[qt] = uk.v;
        }
    }

    // ---------- phase 2: attention; per-qt softmax (tree reduce) -> pack -> PV ----------
    v4f oT[2][4];   // [ntl][qt]: O[query=16qt+l15][d=16ntl+4g+r]
    #pragma unroll
    for (int ntl = 0; ntl < 2; ++ntl)
        #pragma unroll
        for (int qt = 0; qt < 4; ++qt)
            oT[ntl][qt] = (v4f){0.f,0.f,0.f,0.f};
    const float* bt = biasT + h*4096;
    #pragma unroll
    for (int qt = 0; qt < 4; ++qt) {
        v4f bb[4];
        #pragma unroll
        for (int kt = 0; kt < 4; ++kt)
            bb[kt] = *(const v4f*)&bt[(qt*16 + l15)*64 + kt*16 + 4*g];
        v4f sq[4];
        __builtin_amdgcn_s_setprio(1);
        #pragma unroll
        for (int kt = 0; kt < 4; ++kt)
            sq[kt] = __builtin_amdgcn_mfma_f32_16x16x32_bf16(kfr[kt], qfr[qt], bb[kt], 0, 0, 0);
        __builtin_amdgcn_s_setprio(0);
        // tree max (per-kt max4, then combine — ILP-friendly, v_max3-fusable)
        float m0 = fmaxf(fmaxf(sq[0][0], sq[0][1]), fmaxf(sq[0][2], sq[0][3]));
        float m1 = fmaxf(fmaxf(sq[1][0], sq[1][1]), fmaxf(sq[1][2], sq[1][3]));
        float m2 = fmaxf(fmaxf(sq[2][0], sq[2][1]), fmaxf(sq[2][2], sq[2][3]));
        float m3 = fmaxf(fmaxf(sq[3][0], sq[3][1]), fmaxf(sq[3][2], sq[3][3]));
        float mx = fmaxf(fmaxf(m0, m1), fmaxf(m2, m3));
        mx = fmaxf(mx, __shfl_xor(mx, 16));
        mx = fmaxf(mx, __shfl_xor(mx, 32));
        float s0 = 0.f, s1 = 0.f;
        #pragma unroll
        for (int kt = 0; kt < 4; ++kt)
            #pragma unroll
            for (int r = 0; r < 4; ++r) {
                float e = __expf(sq[kt][r] - mx);
                sq[kt][r] = e;
                if (kt < 2) s0 += e; else s1 += e;
            }
        float sum = s0 + s1;
        sum += __shfl_xor(sum, 16);
        sum += __shfl_xor(sum, 32);
        float inv = 1.f / sum;
        #pragma unroll
        for (int kt = 0; kt < 4; ++kt)
            #pragma unroll
            for (int r = 0; r < 4; ++r) sq[kt][r] *= inv;

        union { v8s v; uint32_t d[4]; } p0, p1;
        p0.d[0] = pk2(sq[0][0], sq[0][1]); p0.d[1] = pk2(sq[0][2], sq[0][3]);
        p0.d[2] = pk2(sq[1][0], sq[1][1]); p0.d[3] = pk2(sq[1][2], sq[1][3]);
        p1.d[0] = pk2(sq[2][0], sq[2][1]); p1.d[1] = pk2(sq[2][2], sq[2][3]);
        p1.d[2] = pk2(sq[3][0], sq[3][1]); p1.d[3] = pk2(sq[3][2], sq[3][3]);
        __builtin_amdgcn_s_setprio(1);
        #pragma unroll
        for (int ntl = 0; ntl < 2; ++ntl) {
            oT[ntl][qt] = __builtin_amdgcn_mfma_f32_16x16x32_bf16(vfr[0][ntl], p0.v, oT[ntl][qt], 0, 0, 0);
            oT[ntl][qt] = __builtin_amdgcn_mfma_f32_16x16x32_bf16(vfr[1][ntl], p1.v, oT[ntl][qt], 0, 0, 0);
        }
        __builtin_amdgcn_s_setprio(0);
    }

    // attn_out -> bO [64][AO_STR], b64 stores
    #pragma unroll
    for (int qt = 0; qt < 4; ++qt)
        #pragma unroll
        for (int ntl = 0; ntl < 2; ++ntl) {
            v2u o;
            o.x = pk2(oT[ntl][qt][0], oT[ntl][qt][1]);
            o.y = pk2(oT[ntl][qt][2], oT[ntl][qt][3]);
            *(v2u*)&bO[(qt*16 + l15)*AO_STR + h*32 + ntl*16 + 4*g] = o;
        }
    __syncthreads();   // B2: both AO tiles complete

    // ---------- phase 3: transposed proj GEMM (kk rolled, bias as acc init) + reg scatter ----------
    v4f pbv[2];
    #pragma unroll
    for (int ntl = 0; ntl < 2; ++ntl)
        pbv[ntl] = *(const v4f*)&proj_b[h*32 + ntl*16 + 4*g];
    v4f pacc[2][4];
    #pragma unroll
    for (int ntl = 0; ntl < 2; ++ntl)
        #pragma unroll
        for (int qt = 0; qt < 4; ++qt)
            pacc[ntl][qt] = pbv[ntl];
    #pragma unroll 1
    for (int kk = 0; kk < 6; ++kk) {
        v8s aofr[4];
        #pragma unroll
        for (int qt = 0; qt < 4; ++qt)
            aofr[qt] = *(const v8s*)&bO[(qt*16 + l15)*AO_STR + kk*32 + g*8];
        v8s pwfr[2];
        #pragma unroll
        for (int ntl = 0; ntl < 2; ++ntl)
            pwfr[ntl] = *(const v8s*)(pw + (size_t)(h*32 + ntl*16 + l15)*DIM + kk*32 + g*8);
        __builtin_amdgcn_s_setprio(1);
        #pragma unroll
        for (int ntl = 0; ntl < 2; ++ntl)
            #pragma unroll
            for (int qt = 0; qt < 4; ++qt)
                pacc[ntl][qt] = __builtin_amdgcn_mfma_f32_16x16x32_bf16(pwfr[ntl], aofr[qt], pacc[ntl][qt], 0, 0, 0);
        __builtin_amdgcn_s_setprio(0);
    }

    #pragma unroll
    for (int qt = 0; qt < 4; ++qt) {
        const int strow = 2*qt + (l15 >> 3);
        const int stcol = l15 & 7;
        int hh = wi*8 + strow + 4; if (hh >= IMG) hh -= IMG;
        int ww = wj*8 + stcol + 4; if (ww >= IMG) ww -= IMG;
        const size_t pix = (size_t)hh*IMG + ww;
        #pragma unroll
        for (int ntl = 0; ntl < 2; ++ntl)
            #pragma unroll
            for (int r = 0; r < 4; ++r) {
                const int c = h*32 + ntl*16 + 4*g + r;
                ob[(size_t)c*(IMG*IMG) + pix] = pacc[ntl][qt][r];
            }
    }
}

extern "C" void kernel_launch(void* const* d_in, const int* in_sizes, int n_in,
                              void* d_out, int out_size, void* d_ws, size_t ws_size,
                              hipStream_t stream) {
    const float* x        = (const float*)d_in[0];
    const float* qkv_w    = (const float*)d_in[1];
    const float* qkv_b    = (const float*)d_in[2];
    const float* proj_w   = (const float*)d_in[3];
    const float* proj_b   = (const float*)d_in[4];
    const float* rel_bias = (const float*)d_in[5];
    const int*   rel_idx  = (const int*)d_in[6];

    u16*   qw_bf  = (u16*)d_ws;                         // 221184 B
    u16*   pw_bf  = (u16*)((char*)d_ws + 221184);       //  73728 B
    float* qb2    = (float*)((char*)d_ws + 294912);     //   2304 B
    float* biasT  = (float*)((char*)d_ws + 297216);     //  98304 B
    float* out    = (float*)d_out;

    hipLaunchKernelGGL(prep_kernel, dim3(432), dim3(256), 0, stream,
                       qkv_w, qkv_b, proj_w, rel_bias, rel_idx, qw_bf, pw_bf, qb2, biasT);
    hipLaunchKernelGGL(winattn_kernel, dim3(NB * (NWIN*NWIN/2)), dim3(768), 0, stream,
                       x, proj_b, qw_bf, pw_bf, qb2, biasT, out);
}